// Round 1
// baseline (903.096 us; speedup 1.0000x reference)
//
#include <hip/hip_runtime.h>
#include <hip/hip_bf16.h>
#include <cstdint>
#include <cstddef>

// Problem constants
#define BATCH   8192
#define DIM     768
#define NTOT    6291456      // BATCH*DIM
#define NLAYERS 4

typedef _Float16 half8 __attribute__((ext_vector_type(8)));
typedef _Float16 half4 __attribute__((ext_vector_type(4)));
typedef float    f32x4 __attribute__((ext_vector_type(4)));

#define AS_GLOBAL __attribute__((address_space(1)))
#define AS_LDS    __attribute__((address_space(3)))

// async 16B global->LDS copy; lds dst is wave-uniform base + lane*16
__device__ __forceinline__ void async_copy16(const void* g, void* l) {
  __builtin_amdgcn_global_load_lds((AS_GLOBAL const uint32_t*)g,
                                   (AS_LDS uint32_t*)l, 16, 0, 0);
}

// ---------------------------------------------------------------------------
// Threefry-2x32 (matches jax/_src/prng.py exactly; 20 rounds, 5 key injections)
// ---------------------------------------------------------------------------
__host__ __device__ __forceinline__ uint32_t rotl32(uint32_t v, int d) {
  return (v << d) | (v >> (32 - d));
}

__host__ __device__ __forceinline__ void threefry2x32(
    uint32_t k0, uint32_t k1, uint32_t x0, uint32_t x1,
    uint32_t& o0, uint32_t& o1) {
  uint32_t ks2 = k0 ^ k1 ^ 0x1BD11BDAu;
  x0 += k0; x1 += k1;
#define TF_R(r) { x0 += x1; x1 = rotl32(x1, (r)) ^ x0; }
  TF_R(13) TF_R(15) TF_R(26) TF_R(6)
  x0 += k1; x1 += ks2 + 1u;
  TF_R(17) TF_R(29) TF_R(16) TF_R(24)
  x0 += ks2; x1 += k0 + 2u;
  TF_R(13) TF_R(15) TF_R(26) TF_R(6)
  x0 += k0; x1 += k1 + 3u;
  TF_R(17) TF_R(29) TF_R(16) TF_R(24)
  x0 += k1; x1 += ks2 + 4u;
  TF_R(13) TF_R(15) TF_R(26) TF_R(6)
  x0 += ks2; x1 += k0 + 5u;
#undef TF_R
  o0 = x0; o1 = x1;
}

__device__ __forceinline__ double sigmoid_d(double x) {
  return 1.0 / (1.0 + exp(-x));
}

// fast f64 e^x, |x| clamped to 708, rel err ~2e-13 (need only ~1e-9:
// JAX's own f32 sigmoid carries ~1e-7 error, flips are dominated by that)
__device__ __forceinline__ double dexp(double x) {
  x = fmin(fmax(x, -708.0), 708.0);
  const double LOG2E = 1.4426950408889634;
  const double LN2   = 0.6931471805599453;
  double t = x * LOG2E;
  double n = rint(t);
  double g = (t - n) * LN2;            // |g| <= 0.3466
  double r = 2.7557319223985893e-07;   // 1/10!
  r = r * g + 2.7557319223985888e-06;  // 1/9!
  r = r * g + 2.4801587301587302e-05;  // 1/8!
  r = r * g + 1.9841269841269841e-04;  // 1/7!
  r = r * g + 1.3888888888888889e-03;  // 1/6!
  r = r * g + 8.3333333333333332e-03;  // 1/5!
  r = r * g + 4.1666666666666664e-02;  // 1/4!
  r = r * g + 1.6666666666666666e-01;  // 1/3!
  r = r * g + 0.5;
  r = r * g + 1.0;
  r = r * g + 1.0;
  int ni = (int)n;
  double sc = __longlong_as_double(((long long)(1023 + ni)) << 52);
  return r * sc;
}

// ---------------------------------------------------------------------------
// Kernel 1: embedding gather -> x as f16 hi/lo pairs, vectorized x4.
// Also zeroes the f64 accumulators (runs first in stream order).
// ---------------------------------------------------------------------------
__global__ __launch_bounds__(256) void gather_kernel(
    const int* __restrict__ x_p, const int* __restrict__ x_a,
    const int* __restrict__ x_c,
    const float* __restrict__ E0, const float* __restrict__ E1,
    const float* __restrict__ E2,
    _Float16* __restrict__ xdh, _Float16* __restrict__ xdl,
    _Float16* __restrict__ xsh, _Float16* __restrict__ xsl,
    double* __restrict__ stats, double* __restrict__ bce_acc) {
  if (blockIdx.x == 0 && threadIdx.x < 18) {
    if (threadIdx.x < 16) stats[threadIdx.x] = 0.0;
    else bce_acc[threadIdx.x - 16] = 0.0;
  }
  int j4  = blockIdx.x * 256 + threadIdx.x;   // group of 4 elements
  int idx = j4 * 4;
  int b = idx / DIM;
  int f = idx - b * DIM;          // multiple of 4; 4-group never crosses table
  int half_ = f / 384;            // 0 or 1
  int w = f - half_ * 384;        // 0..383
  int t = w >> 7;                 // table 0..2
  int c = (w & 127) + (half_ << 7);
  int row;
  const float* E;
  if (t == 0)      { E = E0; row = x_p[b]; }
  else if (t == 1) { E = E1; row = x_a[b]; }
  else             { E = E2; row = x_c[b]; }
  f32x4 v = *(const f32x4*)&E[(size_t)row * 256 + c];
  half4 h, l;
#pragma unroll
  for (int i = 0; i < 4; ++i) {
    h[i] = (_Float16)v[i];
    l[i] = (_Float16)(v[i] - (float)h[i]);
  }
  *(half4*)&xdh[idx] = h; *(half4*)&xdl[idx] = l;
  *(half4*)&xsh[idx] = h; *(half4*)&xsl[idx] = l;
}

// ---------------------------------------------------------------------------
// Kernel 1b: split all W (both nets, all layers) into f16 hi/lo
// ---------------------------------------------------------------------------
__global__ __launch_bounds__(256) void split_w_kernel(
    const float* __restrict__ Wd, const float* __restrict__ Ws,
    _Float16* __restrict__ Wh, _Float16* __restrict__ Wl) {
  int idx = blockIdx.x * 256 + threadIdx.x;    // 0 .. 2*4*768*768-1
  const int perNet = NLAYERS * DIM * DIM;
  float v = (idx < perNet) ? Wd[idx] : Ws[idx - perNet];
  _Float16 h = (_Float16)v;
  Wh[idx] = h;
  Wl[idx] = (_Float16)(v - (float)h);
}

// ---------------------------------------------------------------------------
// Kernel 2: MFMA GEMM, f16 hi/lo 3-term split.
//   cross[m][n] = sum_k X[m][k] * W[n][k] + bias[n]
// 128x384 block tile, BK=32, 512 threads = 8 waves (2m x 4n), wave = 64x96.
// Grid (64 m, 2 n, 2 net) = 256 blocks = exactly 1 block/CU.
// LDS: double-buffered, 2 x 64KB. Per buffer (granule = 8 halves = 16B):
//   [Ah 512 | Al 512 | Bh 1536 | Bl 1536] granules; within each array the
//   layout is TRANSPOSED: slot = kk*ROWS + row  (kk = k-granule 0..3).
//   -> frag ds_read_b128: consecutive l16 = consecutive granules =
//      conflict-free; staging stays lane-linear as global_load_lds requires.
// 2-phase pipeline: stage(k+1) issued BEFORE compute(k); one __syncthreads
// per K-step (drains vmcnt(0) ~2800 cyc after issue -> latency hidden).
// acc += Ah*Bh + Al*Bh + Ah*Bl   (lo*lo dropped, ~2^-22 relative)
// Epilogue: bias, C store, f64 sum/sumsq -> atomicAdd into stats slot
// (replaces the partials buffer + finalize_stats kernel).
// ---------------------------------------------------------------------------
__global__ __launch_bounds__(512, 2) void gemm_mfma_kernel(
    const _Float16* __restrict__ xdh, const _Float16* __restrict__ xdl,
    const _Float16* __restrict__ xsh, const _Float16* __restrict__ xsl,
    const _Float16* __restrict__ Wh, const _Float16* __restrict__ Wl,
    const float* __restrict__ bd, const float* __restrict__ bs,
    float* __restrict__ crd, float* __restrict__ crs,
    double* __restrict__ stats, int layer) {
  const int net = blockIdx.z;
  const float* bias = (net ? bs : bd) + layer * DIM;
  float* C = net ? crs : crd;

  const int tid  = threadIdx.x;
  const int wave = tid >> 6, lane = tid & 63;
  const int quad = lane >> 4, l16 = lane & 15;
  const int m0 = blockIdx.x * 128;
  const int n0 = blockIdx.y * 384;

  __shared__ _Float16 lds[2][32768];   // 2 x 64 KB
  __shared__ double red[8][2];

  // ---- staging setup: wave w stages one 512-granule chunk ----
  const _Float16* gbase;
  int chunkoff, rows, rowbase;
  if (wave == 0)      { gbase = net ? xsh : xdh; chunkoff = 0; rows = 128; rowbase = m0; }
  else if (wave == 1) { gbase = net ? xsl : xdl; chunkoff = 0; rows = 128; rowbase = m0; }
  else if (wave < 5)  { gbase = Wh + ((size_t)net * NLAYERS + layer) * DIM * DIM;
                        chunkoff = (wave - 2) * 512; rows = 384; rowbase = n0; }
  else                { gbase = Wl + ((size_t)net * NLAYERS + layer) * DIM * DIM;
                        chunkoff = (wave - 5) * 512; rows = 384; rowbase = n0; }
  int soff[8];                         // k-invariant per-lane source offsets
#pragma unroll
  for (int j = 0; j < 8; ++j) {
    int s  = chunkoff + j * 64 + lane; // granule slot within this buffer chunk
    int kk = s / rows;                 // transposed layout: slot = kk*rows+row
    int r  = s - kk * rows;
    soff[j] = (rowbase + r) * DIM + kk * 8;
  }
  const int ldsbase = wave * 4096;     // halves (wave*512 granules * 8)

  const int wm = (wave >> 2) * 64;     // wave row   (2 in m)
  const int wn = (wave & 3) * 96;      // wave col   (4 in n)

  f32x4 acc[4][6];
#pragma unroll
  for (int i = 0; i < 4; ++i)
#pragma unroll
    for (int j = 0; j < 6; ++j) acc[i][j] = (f32x4){0.f, 0.f, 0.f, 0.f};

  // prologue: stage k0=0 into buffer 0
#pragma unroll
  for (int j = 0; j < 8; ++j)
    async_copy16(gbase + soff[j], &lds[0][ldsbase + j * 512]);
  __syncthreads();

  int cur = 0;
  for (int s = 0; s < 24; ++s) {
    if (s < 23) {                      // issue next-tile stage FIRST
      const int k0n = (s + 1) * 32;
#pragma unroll
      for (int j = 0; j < 8; ++j)
        async_copy16(gbase + soff[j] + k0n, &lds[cur ^ 1][ldsbase + j * 512]);
    }
    half8 ah[4], al[4];
#pragma unroll
    for (int mt = 0; mt < 4; ++mt) {
      int g = quad * 128 + wm + mt * 16 + l16;   // conflict-free: l16-linear
      ah[mt] = *(const half8*)&lds[cur][g * 8];
      al[mt] = *(const half8*)&lds[cur][4096 + g * 8];
    }
    __builtin_amdgcn_s_setprio(1);
#pragma unroll
    for (int nt = 0; nt < 6; ++nt) {
      int g = quad * 384 + wn + nt * 16 + l16;
      half8 bh = *(const half8*)&lds[cur][8192  + g * 8];
      half8 bl = *(const half8*)&lds[cur][20480 + g * 8];
#pragma unroll
      for (int mt = 0; mt < 4; ++mt) {
        f32x4 a = acc[mt][nt];
        a = __builtin_amdgcn_mfma_f32_16x16x32_f16(ah[mt], bh, a, 0, 0, 0);
        a = __builtin_amdgcn_mfma_f32_16x16x32_f16(al[mt], bh, a, 0, 0, 0);
        a = __builtin_amdgcn_mfma_f32_16x16x32_f16(ah[mt], bl, a, 0, 0, 0);
        acc[mt][nt] = a;
      }
    }
    __builtin_amdgcn_s_setprio(0);
    __syncthreads();                   // drains vmcnt(0): next buffer ready
    cur ^= 1;
  }

  // epilogue: bias add, store, f64 sum/sumsq -> atomics
  float biasv[6];
#pragma unroll
  for (int nt = 0; nt < 6; ++nt) biasv[nt] = bias[n0 + wn + nt * 16 + l16];

  double S = 0.0, Q = 0.0;
#pragma unroll
  for (int mt = 0; mt < 4; ++mt) {
#pragma unroll
    for (int nt = 0; nt < 6; ++nt) {
      int n = n0 + wn + nt * 16 + l16;
#pragma unroll
      for (int r = 0; r < 4; ++r) {
        int m = m0 + wm + mt * 16 + quad * 4 + r;
        float v = acc[mt][nt][r] + biasv[nt];
        C[(size_t)m * DIM + n] = v;
        S += (double)v;
        Q += (double)v * (double)v;
      }
    }
  }
#pragma unroll
  for (int off = 32; off > 0; off >>= 1) {
    S += __shfl_down(S, off);
    Q += __shfl_down(Q, off);
  }
  if (lane == 0) { red[wave][0] = S; red[wave][1] = Q; }
  __syncthreads();
  if (tid == 0) {
    double s2 = 0.0, q2 = 0.0;
#pragma unroll
    for (int wv = 0; wv < 8; ++wv) { s2 += red[wv][0]; q2 += red[wv][1]; }
    double* st = stats + ((size_t)layer * 2 + net) * 2;
    atomicAdd(&st[0], s2);
    atomicAdd(&st[1], q2);
  }
}

// ---------------------------------------------------------------------------
// Kernel 4: full-tensor layernorm -> sigmoid -> threefry bernoulli mask ->
//           x += cross*mask. Vectorized x8; f64 exp via dexp; no f64 divide:
//           u < 1/(1+e)  <=>  u + u*e < 1.
// ---------------------------------------------------------------------------
__global__ __launch_bounds__(256) void mask_update_kernel(
    _Float16* __restrict__ xdh, _Float16* __restrict__ xdl,
    _Float16* __restrict__ xsh, _Float16* __restrict__ xsl,
    const float* __restrict__ crd, const float* __restrict__ crs,
    const double* __restrict__ stats, int layer,
    uint32_t kd0, uint32_t kd1, uint32_t ks0, uint32_t ks1) {
  const int net = blockIdx.y;
  _Float16* xh = net ? xsh : xdh;
  _Float16* xl = net ? xsl : xdl;
  const float* cr = net ? crs : crd;
  const uint32_t k0 = net ? ks0 : kd0;
  const uint32_t k1 = net ? ks1 : kd1;

  const double invN = 1.0 / (double)NTOT;
  const double* st = stats + ((size_t)layer * 2 + net) * 2;
  double meand = st[0] * invN;
  double vard  = st[1] * invN - meand * meand;
  float m  = (float)meand;
  float v  = (float)vard;
  float sv = v + 1e-5f;
  float rs = (float)(1.0 / sqrt((double)sv));

  uint32_t j0 = (blockIdx.x * 256u + threadIdx.x) * 8u;
  float cc[8];
  *(f32x4*)&cc[0] = *(const f32x4*)&cr[j0];
  *(f32x4*)&cc[4] = *(const f32x4*)&cr[j0 + 4];
  half8 h8 = *(const half8*)&xh[j0];
  half8 l8 = *(const half8*)&xl[j0];
  half8 ho, lo;
#pragma unroll
  for (int i = 0; i < 8; ++i) {
    float c  = cc[i];
    float ln = (c - m) * rs;
    uint32_t o0, o1;
    threefry2x32(k0, k1, 0u, j0 + (uint32_t)i, o0, o1);
    uint32_t bits = o0 ^ o1;
    float u = __uint_as_float(0x3F800000u | (bits >> 9)) - 1.0f;
    double e  = dexp(-(double)ln);
    double ue = (double)u;
    float xv = (float)h8[i] + (float)l8[i];   // exact fp32 reconstruction
    if (ue + ue * e < 1.0) xv += c;           // u < sigmoid(ln)
    _Float16 hh = (_Float16)xv;
    ho[i] = hh;
    lo[i] = (_Float16)(xv - (float)hh);
  }
  *(half8*)&xh[j0] = ho;
  *(half8*)&xl[j0] = lo;
}

// ---------------------------------------------------------------------------
// Kernel 5: heads. One wave per row: 4 dot products (half8-vectorized),
// sigmoids, y_pred_d, f64 BCE via atomics.
// ---------------------------------------------------------------------------
__global__ __launch_bounds__(256) void head_kernel(
    const _Float16* __restrict__ xdh, const _Float16* __restrict__ xdl,
    const _Float16* __restrict__ xsh, const _Float16* __restrict__ xsl,
    const float* __restrict__ wfd, const float* __restrict__ wfs,
    const float* __restrict__ bfd_p, const float* __restrict__ bfs_p,
    const float* __restrict__ y_true,
    float* __restrict__ out, double* __restrict__ bce_acc) {
  const int wave = threadIdx.x >> 6;
  const int lane = threadIdx.x & 63;
  const int row = blockIdx.x * 4 + wave;
  const size_t base = (size_t)row * DIM;

  float dd = 0.f, dsw = 0.f, sd = 0.f, ssw = 0.f;
  for (int cb = lane; cb < 96; cb += 64) {     // 96 chunks of 8 halves
    half8 hd = *(const half8*)&xdh[base + cb * 8];
    half8 ld = *(const half8*)&xdl[base + cb * 8];
    half8 hs = *(const half8*)&xsh[base + cb * 8];
    half8 ls = *(const half8*)&xsl[base + cb * 8];
#pragma unroll
    for (int i = 0; i < 8; ++i) {
      float vd = (float)hd[i] + (float)ld[i];
      float vs = (float)hs[i] + (float)ls[i];
      float wd = wfd[cb * 8 + i], ws = wfs[cb * 8 + i];
      dd  = fmaf(vd, wd, dd);
      dsw = fmaf(vd, ws, dsw);
      sd  = fmaf(vs, wd, sd);
      ssw = fmaf(vs, ws, ssw);
    }
  }
#pragma unroll
  for (int off = 32; off > 0; off >>= 1) {
    dd  += __shfl_down(dd, off);
    dsw += __shfl_down(dsw, off);
    sd  += __shfl_down(sd, off);
    ssw += __shfl_down(ssw, off);
  }
  __shared__ double redd[4], reds[4];
  if (lane == 0) {
    float bfd = *bfd_p, bfs = *bfs_p;
    double sdd = sigmoid_d((double)(dd + bfd));    // fc_d(x_d)
    double ssd = sigmoid_d((double)(dsw + bfs));   // fc_s(x_d)
    double sds = sigmoid_d((double)(sd + bfd));    // fc_d(x_s)
    double sss = sigmoid_d((double)(ssw + bfs));   // fc_s(x_s)
    double ypd = 0.5 * (sdd + sss);
    double yps = 0.5 * (sds + ssd);
    out[row] = (float)ypd;
    double y = (double)y_true[row];
    redd[wave] = -(y * log(ypd) + (1.0 - y) * log(1.0 - ypd));
    reds[wave] = -(y * log(yps) + (1.0 - y) * log(1.0 - yps));
  }
  __syncthreads();
  if (threadIdx.x == 0) {
    atomicAdd(&bce_acc[0], redd[0] + redd[1] + redd[2] + redd[3]);
    atomicAdd(&bce_acc[1], reds[0] + reds[1] + reds[2] + reds[3]);
  }
}

// ---------------------------------------------------------------------------
// Kernel 6: tri_loss from the two BCE accumulators
// ---------------------------------------------------------------------------
__global__ void loss_kernel(const double* __restrict__ bce_acc,
                            float* __restrict__ out_tri) {
  if (threadIdx.x == 0) {
    double loss_d = bce_acc[0] / (double)BATCH;
    double loss_s = bce_acc[1] / (double)BATCH;
    double bce = loss_d + loss_s;
    double wd = fmax(0.0, loss_d - bce);
    double ws = fmax(0.0, loss_s - bce);
    out_tri[0] = (float)(bce + wd * loss_d + ws * loss_s);
  }
}

// ---------------------------------------------------------------------------
// Launch
// ---------------------------------------------------------------------------
extern "C" void kernel_launch(void* const* d_in, const int* in_sizes, int n_in,
                              void* d_out, int out_size, void* d_ws, size_t ws_size,
                              hipStream_t stream) {
  const int* x_p = (const int*)d_in[0];
  const int* x_a = (const int*)d_in[1];
  const int* x_c = (const int*)d_in[2];
  const float* y_true = (const float*)d_in[3];
  const float* E0 = (const float*)d_in[4];
  const float* E1 = (const float*)d_in[5];
  const float* E2 = (const float*)d_in[6];
  const float* Wd = (const float*)d_in[7];
  const float* bd = (const float*)d_in[8];
  const float* Ws = (const float*)d_in[9];
  const float* bs = (const float*)d_in[10];
  const float* wfd = (const float*)d_in[11];
  const float* bfd = (const float*)d_in[12];
  const float* wfs = (const float*)d_in[13];
  const float* bfs = (const float*)d_in[14];
  float* out = (float*)d_out;

  // workspace layout (bytes; doubles 8B-aligned)
  char* p = (char*)d_ws;
  float* crd = (float*)p;                 p += (size_t)NTOT * 4;
  float* crs = (float*)p;                 p += (size_t)NTOT * 4;
  double* stats   = (double*)p;           p += (size_t)16 * 8;   // [layer][net][S,Q]
  double* bce_acc = (double*)p;           p += (size_t)2 * 8;
  _Float16* xdh = (_Float16*)p;           p += (size_t)NTOT * 2;
  _Float16* xdl = (_Float16*)p;           p += (size_t)NTOT * 2;
  _Float16* xsh = (_Float16*)p;           p += (size_t)NTOT * 2;
  _Float16* xsl = (_Float16*)p;           p += (size_t)NTOT * 2;
  _Float16* Wh  = (_Float16*)p;           p += (size_t)2 * NLAYERS * DIM * DIM * 2;
  _Float16* Wl  = (_Float16*)p;           p += (size_t)2 * NLAYERS * DIM * DIM * 2;

  gather_kernel<<<NTOT / 1024, 256, 0, stream>>>(
      x_p, x_a, x_c, E0, E1, E2, xdh, xdl, xsh, xsl, stats, bce_acc);
  split_w_kernel<<<2 * NLAYERS * DIM * DIM / 256, 256, 0, stream>>>(Wd, Ws, Wh, Wl);

  for (int l = 0; l < NLAYERS; ++l) {
    gemm_mfma_kernel<<<dim3(64, 2, 2), 512, 0, stream>>>(
        xdh, xdl, xsh, xsl, Wh, Wl, bd, bs, crd, crs, stats, l);
    uint32_t kd0, kd1, ks0, ks1;
    threefry2x32(0u, 42u, 0u, (uint32_t)l, kd0, kd1);
    threefry2x32(0u, 42u, 0u, (uint32_t)(4 + l), ks0, ks1);
    mask_update_kernel<<<dim3(NTOT / 2048, 2), 256, 0, stream>>>(
        xdh, xdl, xsh, xsl, crd, crs, stats, l, kd0, kd1, ks0, ks1);
  }

  head_kernel<<<BATCH / 4, 256, 0, stream>>>(
      xdh, xdl, xsh, xsl, wfd, wfs, bfd, bfs, y_true, out, bce_acc);
  loss_kernel<<<1, 64, 0, stream>>>(bce_acc, out + BATCH);
}

// Round 2
// 667.909 us; speedup vs baseline: 1.3521x; 1.3521x over previous
//
#include <hip/hip_runtime.h>
#include <hip/hip_bf16.h>
#include <cstdint>
#include <cstddef>

// Problem constants
#define BATCH   8192
#define DIM     768
#define NTOT    6291456      // BATCH*DIM
#define NLAYERS 4

typedef _Float16 half8 __attribute__((ext_vector_type(8)));
typedef float    f32x4 __attribute__((ext_vector_type(4)));

#define AS_GLOBAL __attribute__((address_space(1)))
#define AS_LDS    __attribute__((address_space(3)))

// async 16B global->LDS copy; lds dst is wave-uniform base + lane*16
__device__ __forceinline__ void async_copy16(const void* g, void* l) {
  __builtin_amdgcn_global_load_lds((AS_GLOBAL const uint32_t*)g,
                                   (AS_LDS uint32_t*)l, 16, 0, 0);
}

// ---------------------------------------------------------------------------
// Swizzled global layouts (granule = 8 halves = 16B):
//   x*:  [t 24][kk 4][b 8192][8]          granule idx = (t*4+kk)*8192 + b
//   W*:  [net][layer][t 24][kk 4][row 768][8]
//   cr*: [g16 48][b 8192][16 floats]      g16 = f>>4  (64B granule)
// logical element (b, f): t = f>>5, kk = (f>>3)&3, e = f&7
// ---------------------------------------------------------------------------

// ---------------------------------------------------------------------------
// Threefry-2x32 (matches jax/_src/prng.py exactly; 20 rounds, 5 key injections)
// ---------------------------------------------------------------------------
__host__ __device__ __forceinline__ uint32_t rotl32(uint32_t v, int d) {
  return (v << d) | (v >> (32 - d));
}

__host__ __device__ __forceinline__ void threefry2x32(
    uint32_t k0, uint32_t k1, uint32_t x0, uint32_t x1,
    uint32_t& o0, uint32_t& o1) {
  uint32_t ks2 = k0 ^ k1 ^ 0x1BD11BDAu;
  x0 += k0; x1 += k1;
#define TF_R(r) { x0 += x1; x1 = rotl32(x1, (r)) ^ x0; }
  TF_R(13) TF_R(15) TF_R(26) TF_R(6)
  x0 += k1; x1 += ks2 + 1u;
  TF_R(17) TF_R(29) TF_R(16) TF_R(24)
  x0 += ks2; x1 += k0 + 2u;
  TF_R(13) TF_R(15) TF_R(26) TF_R(6)
  x0 += k0; x1 += k1 + 3u;
  TF_R(17) TF_R(29) TF_R(16) TF_R(24)
  x0 += k1; x1 += ks2 + 4u;
  TF_R(13) TF_R(15) TF_R(26) TF_R(6)
  x0 += ks2; x1 += k0 + 5u;
#undef TF_R
  o0 = x0; o1 = x1;
}

__device__ __forceinline__ double sigmoid_d(double x) {
  return 1.0 / (1.0 + exp(-x));
}

// fast f64 e^x, clamped, rel err ~2e-13
__device__ __forceinline__ double dexp(double x) {
  x = fmin(fmax(x, -708.0), 708.0);
  const double LOG2E = 1.4426950408889634;
  const double LN2   = 0.6931471805599453;
  double t = x * LOG2E;
  double n = rint(t);
  double g = (t - n) * LN2;
  double r = 2.7557319223985893e-07;
  r = r * g + 2.7557319223985888e-06;
  r = r * g + 2.4801587301587302e-05;
  r = r * g + 1.9841269841269841e-04;
  r = r * g + 1.3888888888888889e-03;
  r = r * g + 8.3333333333333332e-03;
  r = r * g + 4.1666666666666664e-02;
  r = r * g + 1.6666666666666666e-01;
  r = r * g + 0.5;
  r = r * g + 1.0;
  r = r * g + 1.0;
  int ni = (int)n;
  double sc = __longlong_as_double(((long long)(1023 + ni)) << 52);
  return r * sc;
}

// ---------------------------------------------------------------------------
// Kernel 1: embedding gather -> x (swizzled layout) as f16 hi/lo pairs.
// Thread <-> x granule: gid = g*8192 + b, g = t*4+kk (96 values), b = row.
// Consecutive threads = consecutive b = consecutive granules -> coalesced.
// Also zeroes the f64 accumulators.
// ---------------------------------------------------------------------------
__global__ __launch_bounds__(256) void gather_kernel(
    const int* __restrict__ x_p, const int* __restrict__ x_a,
    const int* __restrict__ x_c,
    const float* __restrict__ E0, const float* __restrict__ E1,
    const float* __restrict__ E2,
    _Float16* __restrict__ xdh, _Float16* __restrict__ xdl,
    _Float16* __restrict__ xsh, _Float16* __restrict__ xsl,
    double* __restrict__ stats, double* __restrict__ bce_acc) {
  if (blockIdx.x == 0 && threadIdx.x < 18) {
    if (threadIdx.x < 16) stats[threadIdx.x] = 0.0;
    else bce_acc[threadIdx.x - 16] = 0.0;
  }
  int gid = blockIdx.x * 256 + threadIdx.x;   // [0, 786432)
  int g = gid >> 13;                          // granule column 0..95
  int b = gid & 8191;
  int f0 = g * 8;
  int half_ = f0 >= 384;
  int w = f0 - 384 * half_;                   // 0..376, mult of 8
  int tbl = w >> 7;
  int c0 = (w & 127) + (half_ << 7);          // col in E row (8-aligned)
  int row;
  const float* E;
  if (tbl == 0)      { E = E0; row = x_p[b]; }
  else if (tbl == 1) { E = E1; row = x_a[b]; }
  else               { E = E2; row = x_c[b]; }
  const float* src = &E[(size_t)row * 256 + c0];
  f32x4 v0 = *(const f32x4*)src;
  f32x4 v1 = *(const f32x4*)(src + 4);
  half8 h, l;
#pragma unroll
  for (int i = 0; i < 4; ++i) {
    h[i] = (_Float16)v0[i];
    l[i] = (_Float16)(v0[i] - (float)h[i]);
    h[i + 4] = (_Float16)v1[i];
    l[i + 4] = (_Float16)(v1[i] - (float)h[i + 4]);
  }
  size_t o = (size_t)gid * 8;
  *(half8*)&xdh[o] = h; *(half8*)&xdl[o] = l;
  *(half8*)&xsh[o] = h; *(half8*)&xsl[o] = l;
}

// ---------------------------------------------------------------------------
// Kernel 1b: split W into f16 hi/lo in swizzled layout
// out granule gid: nl = net*4+layer, then [t][kk][row]; src row-major W.
// ---------------------------------------------------------------------------
__global__ __launch_bounds__(256) void split_w_kernel(
    const float* __restrict__ Wd, const float* __restrict__ Ws,
    _Float16* __restrict__ Wh, _Float16* __restrict__ Wl) {
  int gid = blockIdx.x * 256 + threadIdx.x;   // [0, 589824)
  int nl = gid / 73728;                       // 0..7
  int r3 = gid - nl * 73728;
  int t  = r3 / 3072;
  int r4 = r3 - t * 3072;
  int kk = r4 / 768;
  int row = r4 - kk * 768;
  int k0 = t * 32 + kk * 8;
  const float* src = ((nl < 4) ? Wd : Ws) +
                     ((size_t)(nl & 3) * 768 + row) * 768 + k0;
  f32x4 v0 = *(const f32x4*)src;
  f32x4 v1 = *(const f32x4*)(src + 4);
  half8 h, l;
#pragma unroll
  for (int i = 0; i < 4; ++i) {
    h[i] = (_Float16)v0[i];
    l[i] = (_Float16)(v0[i] - (float)h[i]);
    h[i + 4] = (_Float16)v1[i];
    l[i + 4] = (_Float16)(v1[i] - (float)h[i + 4]);
  }
  size_t o = (size_t)gid * 8;
  *(half8*)&Wh[o] = h;
  *(half8*)&Wl[o] = l;
}

// ---------------------------------------------------------------------------
// Kernel 2: MFMA GEMM, f16 hi/lo 3-term split.
// BM=128, BN=192, BK=32, 256 thr = 4 waves (2m x 2n), wave tile 64x96.
// Grid (64,4,2) = 512 blocks = exactly 2 blocks/CU (LDS 2x40KB = 80KB).
// LDS buffer slot map (granules):
//   [0,512) Ah (kk*128+r) | [512,1024) Al | [1024,1792) Bh (kk*192+r) |
//   [1792,2560) Bl
// Global arrays are pre-swizzled to this exact order -> staging is
// identity-mapped: every global_load_lds reads 64 consecutive granules
// (1KB contiguous) and writes lane-linear LDS. Frag ds_read_b128:
// consecutive l16 = consecutive 16B slots -> 0 bank conflicts (R1-proven).
// 2-phase pipeline: stage(t+1) issued before compute(t), one barrier/step.
// Epilogue: bias, swizzled C store (perfectly coalesced 64B granules),
// f64 sum/sumsq -> atomicAdd into stats[layer][net].
// ---------------------------------------------------------------------------
__global__ __launch_bounds__(256, 2) void gemm_mfma_kernel(
    const _Float16* __restrict__ xdh, const _Float16* __restrict__ xdl,
    const _Float16* __restrict__ xsh, const _Float16* __restrict__ xsl,
    const _Float16* __restrict__ Wh, const _Float16* __restrict__ Wl,
    const float* __restrict__ bd, const float* __restrict__ bs,
    float* __restrict__ crd, float* __restrict__ crs,
    double* __restrict__ stats, int layer) {
  const int net = blockIdx.z;
  const float* bias = (net ? bs : bd) + layer * DIM;
  float* C = net ? crs : crd;

  const int tid  = threadIdx.x;
  const int wave = tid >> 6, lane = tid & 63;
  const int quad = lane >> 4, l16 = lane & 15;
  const int m0 = blockIdx.x * 128;
  const int n0 = blockIdx.y * 192;

  __shared__ _Float16 lds[2 * 20480];   // 2 x 40 KB

  const _Float16* xh = net ? xsh : xdh;
  const _Float16* xl = net ? xsl : xdl;
  const size_t wpanel = ((size_t)net * NLAYERS + layer) * (size_t)(24 * 4 * 768 * 8);
  const _Float16* wh = Wh + wpanel;
  const _Float16* wl = Wl + wpanel;

  // staging: wave w covers slots {dslot0 + j*64 (j<8)} U {dslot8 + (j-8)*64}
  const int dslot0 = (wave == 0) ? 0 : (wave == 1) ? 512 : (wave == 2) ? 1280 : 1920;
  const int dslot8 = (wave == 0) ? 1024 : (wave == 1) ? 1152 : (wave == 2) ? 1792 : 2432;

  const _Float16* gp[10];   // per-lane src pointer at t=0
  int gstr[10];             // halves per t-step
  int dbyte[10];            // lds dst byte offset within buffer (wave-uniform)
#pragma unroll
  for (int j = 0; j < 10; ++j) {
    int sb = (j < 8) ? dslot0 + j * 64 : dslot8 + (j - 8) * 64;
    dbyte[j] = sb * 16;
    int s = sb + lane;
    if (s < 1024) {                    // A (x) granules
      int s2 = s & 511;
      int kk = s2 >> 7, r = s2 & 127;
      gp[j] = ((s < 512) ? xh : xl) + (size_t)(kk * 8192 + m0 + r) * 8;
      gstr[j] = 4 * 8192 * 8;          // 262144
    } else {                           // B (W) granules
      int s2 = s - 1024;
      int s3 = (s2 >= 768) ? s2 - 768 : s2;
      int kk = (s3 * 683) >> 17;       // s3/192, exact for s3<768
      int r  = s3 - kk * 192;
      gp[j] = ((s2 >= 768) ? wl : wh) + (size_t)(kk * 768 + n0 + r) * 8;
      gstr[j] = 4 * 768 * 8;           // 24576
    }
  }

  const int wm = (wave >> 1) * 64;     // 2 m-waves
  const int wn = (wave & 1) * 96;      // 2 n-waves

  f32x4 acc[4][6];
#pragma unroll
  for (int i = 0; i < 4; ++i)
#pragma unroll
    for (int j = 0; j < 6; ++j) acc[i][j] = (f32x4){0.f, 0.f, 0.f, 0.f};

  // prologue: stage t=0 into buffer 0
#pragma unroll
  for (int j = 0; j < 10; ++j)
    async_copy16(gp[j], (char*)lds + dbyte[j]);
  __syncthreads();

  int cur = 0;
  for (int t = 0; t < 24; ++t) {
    if (t < 23) {                      // issue next-tile stage FIRST
#pragma unroll
      for (int j = 0; j < 10; ++j)
        async_copy16(gp[j] + (t + 1) * gstr[j],
                     (char*)lds + (cur ^ 1) * 40960 + dbyte[j]);
    }
    const _Float16* L = lds + cur * 20480;
    half8 ah[4], al[4];
#pragma unroll
    for (int mt = 0; mt < 4; ++mt) {
      int sl = quad * 128 + wm + mt * 16 + l16;
      ah[mt] = *(const half8*)&L[sl * 8];
      al[mt] = *(const half8*)&L[sl * 8 + 4096];
    }
    __builtin_amdgcn_s_setprio(1);
#pragma unroll
    for (int nt = 0; nt < 6; ++nt) {
      int sl = 1024 + quad * 192 + wn + nt * 16 + l16;
      half8 bh = *(const half8*)&L[sl * 8];
      half8 bl = *(const half8*)&L[sl * 8 + 6144];
#pragma unroll
      for (int mt = 0; mt < 4; ++mt) {
        f32x4 a = acc[mt][nt];
        a = __builtin_amdgcn_mfma_f32_16x16x32_f16(ah[mt], bh, a, 0, 0, 0);
        a = __builtin_amdgcn_mfma_f32_16x16x32_f16(al[mt], bh, a, 0, 0, 0);
        a = __builtin_amdgcn_mfma_f32_16x16x32_f16(ah[mt], bl, a, 0, 0, 0);
        acc[mt][nt] = a;
      }
    }
    __builtin_amdgcn_s_setprio(0);
    __syncthreads();                   // drains vmcnt(0): next buffer ready
    cur ^= 1;
  }

  // epilogue: bias add, swizzled C store, f64 sum/sumsq -> atomics
  float biasv[6];
#pragma unroll
  for (int nt = 0; nt < 6; ++nt) biasv[nt] = bias[n0 + wn + nt * 16 + l16];

  double S = 0.0, Q = 0.0;
#pragma unroll
  for (int mt = 0; mt < 4; ++mt) {
#pragma unroll
    for (int nt = 0; nt < 6; ++nt) {
      int n = n0 + wn + nt * 16 + l16;       // n&15 == l16
      size_t gbase = (size_t)(n >> 4) * 131072;   // granule col * 8192 * 16
#pragma unroll
      for (int r = 0; r < 4; ++r) {
        int m = m0 + wm + mt * 16 + quad * 4 + r;
        float v = acc[mt][nt][r] + biasv[nt];
        C[gbase + m * 16 + l16] = v;
        S += (double)v;
        Q += (double)v * (double)v;
      }
    }
  }
#pragma unroll
  for (int off = 32; off > 0; off >>= 1) {
    S += __shfl_down(S, off);
    Q += __shfl_down(Q, off);
  }
  double* red = (double*)lds;           // reuse LDS (post-final-barrier)
  if (lane == 0) { red[wave * 2] = S; red[wave * 2 + 1] = Q; }
  __syncthreads();
  if (tid == 0) {
    double s2 = 0.0, q2 = 0.0;
#pragma unroll
    for (int wv = 0; wv < 4; ++wv) { s2 += red[wv * 2]; q2 += red[wv * 2 + 1]; }
    double* st = stats + ((size_t)layer * 2 + net) * 2;
    atomicAdd(&st[0], s2);
    atomicAdd(&st[1], q2);
  }
}

// ---------------------------------------------------------------------------
// Kernel 4: layernorm -> sigmoid -> threefry bernoulli -> x += cross*mask.
// Thread <-> one 16-float C granule (64B): cg = g16*8192 + b.
// x granules: (g16*2)*8192 + b and +8192. All accesses coalesced.
// ---------------------------------------------------------------------------
__global__ __launch_bounds__(256) void mask_update_kernel(
    _Float16* __restrict__ xdh, _Float16* __restrict__ xdl,
    _Float16* __restrict__ xsh, _Float16* __restrict__ xsl,
    const float* __restrict__ crd, const float* __restrict__ crs,
    const double* __restrict__ stats, int layer,
    uint32_t kd0, uint32_t kd1, uint32_t ks0, uint32_t ks1) {
  const int net = blockIdx.y;
  _Float16* xh = net ? xsh : xdh;
  _Float16* xl = net ? xsl : xdl;
  const float* cr = net ? crs : crd;
  const uint32_t k0 = net ? ks0 : kd0;
  const uint32_t k1 = net ? ks1 : kd1;

  const double invN = 1.0 / (double)NTOT;
  const double* st = stats + ((size_t)layer * 2 + net) * 2;
  double meand = st[0] * invN;
  double vard  = st[1] * invN - meand * meand;
  float m  = (float)meand;
  float sv = (float)vard + 1e-5f;
  float rs = (float)(1.0 / sqrt((double)sv));

  int cg = blockIdx.x * 256 + threadIdx.x;    // [0, 393216)
  int g16 = cg >> 13;                         // 0..47
  int b   = cg & 8191;
  int f0  = g16 * 16;

  f32x4 c4[4];
#pragma unroll
  for (int i = 0; i < 4; ++i) c4[i] = *(const f32x4*)&cr[(size_t)cg * 16 + i * 4];

  size_t xg0 = ((size_t)g16 * 2) * 8192 + b;
  half8 h0 = *(const half8*)&xh[xg0 * 8];
  half8 l0 = *(const half8*)&xl[xg0 * 8];
  half8 h1 = *(const half8*)&xh[(xg0 + 8192) * 8];
  half8 l1 = *(const half8*)&xl[(xg0 + 8192) * 8];
  half8 ho0, lo0, ho1, lo1;

#pragma unroll
  for (int i = 0; i < 16; ++i) {
    float c  = c4[i >> 2][i & 3];
    float ln = (c - m) * rs;
    uint32_t o0, o1;
    threefry2x32(k0, k1, 0u, (uint32_t)(b * 768 + f0 + i), o0, o1);
    uint32_t bits = o0 ^ o1;
    float u = __uint_as_float(0x3F800000u | (bits >> 9)) - 1.0f;
    double e  = dexp(-(double)ln);
    double ue = (double)u;
    float xv = (i < 8) ? ((float)h0[i & 7] + (float)l0[i & 7])
                       : ((float)h1[i & 7] + (float)l1[i & 7]);
    if (ue + ue * e < 1.0) xv += c;           // u < sigmoid(ln)
    _Float16 hh = (_Float16)xv;
    _Float16 ll = (_Float16)(xv - (float)hh);
    if (i < 8) { ho0[i & 7] = hh; lo0[i & 7] = ll; }
    else       { ho1[i & 7] = hh; lo1[i & 7] = ll; }
  }
  *(half8*)&xh[xg0 * 8] = ho0;
  *(half8*)&xl[xg0 * 8] = lo0;
  *(half8*)&xh[(xg0 + 8192) * 8] = ho1;
  *(half8*)&xl[(xg0 + 8192) * 8] = lo1;
}

// ---------------------------------------------------------------------------
// Kernel 5: heads. One THREAD per row (coalesced granule-major x reads),
// 4 dots in registers, per-thread sigmoids/BCE, block-reduce -> atomics.
// ---------------------------------------------------------------------------
__global__ __launch_bounds__(256) void head_kernel(
    const _Float16* __restrict__ xdh, const _Float16* __restrict__ xdl,
    const _Float16* __restrict__ xsh, const _Float16* __restrict__ xsl,
    const float* __restrict__ wfd, const float* __restrict__ wfs,
    const float* __restrict__ bfd_p, const float* __restrict__ bfs_p,
    const float* __restrict__ y_true,
    float* __restrict__ out, double* __restrict__ bce_acc) {
  int b = blockIdx.x * 256 + threadIdx.x;
  float dd = 0.f, dsw = 0.f, sd = 0.f, ssw = 0.f;
  for (int g = 0; g < 96; ++g) {
    size_t o = ((size_t)g * 8192 + b) * 8;
    half8 hd = *(const half8*)&xdh[o];
    half8 ld = *(const half8*)&xdl[o];
    half8 hs = *(const half8*)&xsh[o];
    half8 ls = *(const half8*)&xsl[o];
#pragma unroll
    for (int i = 0; i < 8; ++i) {
      float vd = (float)hd[i] + (float)ld[i];
      float vs = (float)hs[i] + (float)ls[i];
      float wd = wfd[g * 8 + i], ws = wfs[g * 8 + i];
      dd  = fmaf(vd, wd, dd);
      dsw = fmaf(vd, ws, dsw);
      sd  = fmaf(vs, wd, sd);
      ssw = fmaf(vs, ws, ssw);
    }
  }
  float bfd = *bfd_p, bfs = *bfs_p;
  double sdd = sigmoid_d((double)(dd + bfd));    // fc_d(x_d)
  double ssd = sigmoid_d((double)(dsw + bfs));   // fc_s(x_d)
  double sds = sigmoid_d((double)(sd + bfd));    // fc_d(x_s)
  double sss = sigmoid_d((double)(ssw + bfs));   // fc_s(x_s)
  double ypd = 0.5 * (sdd + sss);
  double yps = 0.5 * (sds + ssd);
  out[b] = (float)ypd;
  double y = (double)y_true[b];
  double bce_d = -(y * log(ypd) + (1.0 - y) * log(1.0 - ypd));
  double bce_s = -(y * log(yps) + (1.0 - y) * log(1.0 - yps));
#pragma unroll
  for (int off = 32; off > 0; off >>= 1) {
    bce_d += __shfl_down(bce_d, off);
    bce_s += __shfl_down(bce_s, off);
  }
  __shared__ double redd[4], reds[4];
  int wave = threadIdx.x >> 6, lane = threadIdx.x & 63;
  if (lane == 0) { redd[wave] = bce_d; reds[wave] = bce_s; }
  __syncthreads();
  if (threadIdx.x == 0) {
    atomicAdd(&bce_acc[0], redd[0] + redd[1] + redd[2] + redd[3]);
    atomicAdd(&bce_acc[1], reds[0] + reds[1] + reds[2] + reds[3]);
  }
}

// ---------------------------------------------------------------------------
// Kernel 6: tri_loss from the two BCE accumulators
// ---------------------------------------------------------------------------
__global__ void loss_kernel(const double* __restrict__ bce_acc,
                            float* __restrict__ out_tri) {
  if (threadIdx.x == 0) {
    double loss_d = bce_acc[0] / (double)BATCH;
    double loss_s = bce_acc[1] / (double)BATCH;
    double bce = loss_d + loss_s;
    double wd = fmax(0.0, loss_d - bce);
    double ws = fmax(0.0, loss_s - bce);
    out_tri[0] = (float)(bce + wd * loss_d + ws * loss_s);
  }
}

// ---------------------------------------------------------------------------
// Launch
// ---------------------------------------------------------------------------
extern "C" void kernel_launch(void* const* d_in, const int* in_sizes, int n_in,
                              void* d_out, int out_size, void* d_ws, size_t ws_size,
                              hipStream_t stream) {
  const int* x_p = (const int*)d_in[0];
  const int* x_a = (const int*)d_in[1];
  const int* x_c = (const int*)d_in[2];
  const float* y_true = (const float*)d_in[3];
  const float* E0 = (const float*)d_in[4];
  const float* E1 = (const float*)d_in[5];
  const float* E2 = (const float*)d_in[6];
  const float* Wd = (const float*)d_in[7];
  const float* bd = (const float*)d_in[8];
  const float* Ws = (const float*)d_in[9];
  const float* bs = (const float*)d_in[10];
  const float* wfd = (const float*)d_in[11];
  const float* bfd = (const float*)d_in[12];
  const float* wfs = (const float*)d_in[13];
  const float* bfs = (const float*)d_in[14];
  float* out = (float*)d_out;

  // workspace layout (bytes; doubles 8B-aligned)
  char* p = (char*)d_ws;
  float* crd = (float*)p;                 p += (size_t)NTOT * 4;
  float* crs = (float*)p;                 p += (size_t)NTOT * 4;
  double* stats   = (double*)p;           p += (size_t)16 * 8;   // [layer][net][S,Q]
  double* bce_acc = (double*)p;           p += (size_t)2 * 8;
  _Float16* xdh = (_Float16*)p;           p += (size_t)NTOT * 2;
  _Float16* xdl = (_Float16*)p;           p += (size_t)NTOT * 2;
  _Float16* xsh = (_Float16*)p;           p += (size_t)NTOT * 2;
  _Float16* xsl = (_Float16*)p;           p += (size_t)NTOT * 2;
  _Float16* Wh  = (_Float16*)p;           p += (size_t)2 * NLAYERS * DIM * DIM * 2;
  _Float16* Wl  = (_Float16*)p;           p += (size_t)2 * NLAYERS * DIM * DIM * 2;

  gather_kernel<<<NTOT / 8 / 256, 256, 0, stream>>>(
      x_p, x_a, x_c, E0, E1, E2, xdh, xdl, xsh, xsl, stats, bce_acc);
  split_w_kernel<<<2 * NLAYERS * DIM * DIM / 8 / 256, 256, 0, stream>>>(
      Wd, Ws, Wh, Wl);

  for (int l = 0; l < NLAYERS; ++l) {
    gemm_mfma_kernel<<<dim3(64, 4, 2), 256, 0, stream>>>(
        xdh, xdl, xsh, xsl, Wh, Wl, bd, bs, crd, crs, stats, l);
    uint32_t kd0, kd1, ks0, ks1;
    threefry2x32(0u, 42u, 0u, (uint32_t)l, kd0, kd1);
    threefry2x32(0u, 42u, 0u, (uint32_t)(4 + l), ks0, ks1);
    mask_update_kernel<<<dim3(NTOT / 16 / 256, 2), 256, 0, stream>>>(
        xdh, xdl, xsh, xsl, crd, crs, stats, l, kd0, kd1, ks0, ks1);
  }

  head_kernel<<<BATCH / 256, 256, 0, stream>>>(
      xdh, xdl, xsh, xsl, wfd, wfs, bfd, bfs, y_true, out, bce_acc);
  loss_kernel<<<1, 64, 0, stream>>>(bce_acc, out + BATCH);
}